// Round 6
// baseline (391.072 us; speedup 1.0000x reference)
//
#include <hip/hip_runtime.h>
#include <math.h>

#define HH 512
#define WW 512
#define NB 64
#define CH_STRIDE (HH*WW)
#define IMG_STRIDE (3*CH_STRIDE)

// 5-tap Gaussian, sigma=1.0 (matches cv2.getGaussianKernel(5,1.0) in f32)
#define GK0 0.0544886846f
#define GK1 0.2442013419f
#define GK2 0.4026199468f

// Workspace layout (floats): [0..383] per-plane (s,q) x192; [384..511] gray (s,q) x64
#define WS_GRAY_OFF 384
#define WS_FLOATS   512

__device__ __forceinline__ float quant255(float v) {
    // floor(clip(v*255, 0, 255)); _rn ops to avoid FMA contraction changing boundaries
    return floorf(fminf(fmaxf(__fmul_rn(v, 255.0f), 0.0f), 255.0f));
}
__device__ __forceinline__ float gray255(float qa, float qb, float qc) {
    // rint = round-half-even, matches jnp.round; stays in x255 domain (no /255)
    return rintf(__fadd_rn(__fadd_rn(__fmul_rn(0.299f, qa), __fmul_rn(0.587f, qb)),
                           __fmul_rn(0.114f, qc)));
}
__device__ __forceinline__ int reflect_row(int r) {
    return (r < 0) ? -r : ((r >= HH) ? (2*(HH-1) - r) : r);
}

// LESSONS (R1-R5, measured):
//  - launch_bounds(256,4) => allocator spill collapse (530 MB scratch). Never set arg2.
//  - VGPR=104 body only reaches ~8 waves/CU residency (Occ ~20%) regardless of grid;
//    VGPR=64 body reached Occ 45%. The residency cliff is at 64 VGPRs -> keep each
//    kernel's loop-carried state to ONE blur ring (~28 regs), not four (~112).
//  - Rolled outer (unroll 1) x inner unroll-5 keeps the ring static without spill.

// ---------------------------------------------------------------------------
// Kernel 1: per-channel float noise (s, q) for 192 channel-planes.
// One wave = 256-col x 16-row strip of one plane (reads 20 rows).
// Grid: 192 planes x 2 strips x 8 chunk-groups = 3072 blocks x 256 thr.
// ---------------------------------------------------------------------------
__global__ __launch_bounds__(256)
void ch_noise(const float* __restrict__ x, float* __restrict__ gsums)
{
    const int tid  = threadIdx.x;
    const int lane = tid & 63;
    const int wid  = tid >> 6;

    const int blk   = blockIdx.x;      // 3072 blocks
    const int plane = blk >> 4;        // 0..191
    const int strip = (blk >> 3) & 1;
    const int cg    = blk & 7;
    const int chunk = cg * 4 + wid;    // 0..31
    const int R0    = chunk * 16;
    const int X0    = strip * 256;
    const int gcol  = X0 + lane * 4;

    const float* p = x + (size_t)plane * CH_STRIDE;

    float hr[5][4];          // horizontal-blur ring
    float d1[4], d2[4];      // raw-center delays
    float s = 0.f, q = 0.f;

    #pragma unroll 1
    for (int tb = 0; tb < 4; ++tb) {
        #pragma unroll
        for (int u = 0; u < 5; ++u) {
            const int t = tb * 5 + u;
            const int rowoff = reflect_row(R0 - 2 + t) * WW;
            const float4 v4 = *(const float4*)(p + rowoff + gcol);

            float l2 = __shfl_up(v4.z, 1), l1 = __shfl_up(v4.w, 1);
            float r0 = __shfl_down(v4.x, 1), r1 = __shfl_down(v4.y, 1);
            if (lane == 0) {
                if (X0 == 0) { l2 = v4.z; l1 = v4.y; }       // reflect-101
                else { float2 e = *(const float2*)(p + rowoff + 254); l2 = e.x; l1 = e.y; }
            }
            if (lane == 63) {
                if (X0 == 0) { float2 e = *(const float2*)(p + rowoff + 256); r0 = e.x; r1 = e.y; }
                else { r0 = v4.z; r1 = v4.y; }               // reflect-101
            }

            hr[u][0] = GK0*(l2+v4.z)  + GK1*(l1+v4.y)   + GK2*v4.x;
            hr[u][1] = GK0*(l1+v4.w)  + GK1*(v4.x+v4.z) + GK2*v4.y;
            hr[u][2] = GK0*(v4.x+r0)  + GK1*(v4.y+v4.w) + GK2*v4.z;
            hr[u][3] = GK0*(v4.y+r1)  + GK1*(v4.z+r0)   + GK2*v4.w;

            if (t >= 4) {
                const int s0=(u+1)%5, s1=(u+2)%5, s2=(u+3)%5, s3=(u+4)%5, s4=u;
                #pragma unroll
                for (int j = 0; j < 4; ++j) {
                    float bl = GK0*(hr[s0][j]+hr[s4][j]) + GK1*(hr[s1][j]+hr[s3][j]) + GK2*hr[s2][j];
                    float v  = d2[j] - bl;
                    s += v;  q = fmaf(v, v, q);
                }
            }
            #pragma unroll
            for (int j = 0; j < 4; ++j) d2[j] = d1[j];
            d1[0]=v4.x; d1[1]=v4.y; d1[2]=v4.z; d1[3]=v4.w;
        }
    }

    #pragma unroll
    for (int o = 32; o > 0; o >>= 1) { s += __shfl_down(s, o); q += __shfl_down(q, o); }
    if (lane == 0) {
        atomicAdd(&gsums[plane*2 + 0], s);
        atomicAdd(&gsums[plane*2 + 1], q);
    }
}

// ---------------------------------------------------------------------------
// Kernel 2: gray noise (s, q) + 50-bin histogram.
// Loads all 3 channels but immediately collapses to gray; shuffles the 4 gray
// values (4 bpermutes/step, not 12). Histogram: 16 lane-group replicas/block.
// Grid: 64 img x 2 strips x 8 chunk-groups = 1024 blocks x 256 thr.
// ---------------------------------------------------------------------------
__global__ __launch_bounds__(256)
void gray_hist(const float* __restrict__ x, float* __restrict__ gsums,
               unsigned int* __restrict__ ghist)
{
    __shared__ unsigned int lhist[16][50];
    const int tid  = threadIdx.x;
    const int lane = tid & 63;
    const int wid  = tid >> 6;
    const int rep  = tid >> 4;            // 16 replicas: wid*4 + (lane>>4)
    for (int i = tid; i < 16*50; i += 256) ((unsigned int*)lhist)[i] = 0u;
    __syncthreads();

    const int blk   = blockIdx.x;      // 1024 blocks
    const int b     = blk >> 4;
    const int strip = (blk >> 3) & 1;
    const int cg    = blk & 7;
    const int chunk = cg * 4 + wid;    // 0..31
    const int R0    = chunk * 16;
    const int X0    = strip * 256;
    const int gcol  = X0 + lane * 4;

    const float* pa = x + (size_t)b * IMG_STRIDE;
    const float* pb = pa + CH_STRIDE;
    const float* pc = pb + CH_STRIDE;

    float hr[5][4];          // gray horizontal-blur ring
    float d1[4], d2[4];      // gray raw-center delays
    float s = 0.f, q = 0.f;

    #pragma unroll 1
    for (int tb = 0; tb < 4; ++tb) {
        #pragma unroll
        for (int u = 0; u < 5; ++u) {
            const int t = tb * 5 + u;
            const int rowoff = reflect_row(R0 - 2 + t) * WW;
            const float4 va = *(const float4*)(pa + rowoff + gcol);
            const float4 vb = *(const float4*)(pb + rowoff + gcol);
            const float4 vc = *(const float4*)(pc + rowoff + gcol);

            // collapse to quantized gray immediately (x255 domain)
            float g0 = gray255(quant255(va.x), quant255(vb.x), quant255(vc.x));
            float g1 = gray255(quant255(va.y), quant255(vb.y), quant255(vc.y));
            float g2 = gray255(quant255(va.z), quant255(vb.z), quant255(vc.z));
            float g3 = gray255(quant255(va.w), quant255(vb.w), quant255(vc.w));

            // halo via shuffles of the GRAY values (4 bpermutes, not 12)
            float gl2 = __shfl_up(g2, 1),  gl1 = __shfl_up(g3, 1);
            float gr0 = __shfl_down(g0, 1), gr1 = __shfl_down(g1, 1);
            if (lane == 0) {
                if (X0 == 0) { gl2 = g2; gl1 = g1; }          // reflect-101
                else {
                    float2 ea = *(const float2*)(pa + rowoff + 254);
                    float2 eb = *(const float2*)(pb + rowoff + 254);
                    float2 ec = *(const float2*)(pc + rowoff + 254);
                    gl2 = gray255(quant255(ea.x), quant255(eb.x), quant255(ec.x));
                    gl1 = gray255(quant255(ea.y), quant255(eb.y), quant255(ec.y));
                }
            }
            if (lane == 63) {
                if (X0 == 0) {
                    float2 ea = *(const float2*)(pa + rowoff + 256);
                    float2 eb = *(const float2*)(pb + rowoff + 256);
                    float2 ec = *(const float2*)(pc + rowoff + 256);
                    gr0 = gray255(quant255(ea.x), quant255(eb.x), quant255(ec.x));
                    gr1 = gray255(quant255(ea.y), quant255(eb.y), quant255(ec.y));
                } else { gr0 = g2; gr1 = g1; }                // reflect-101
            }

            hr[u][0] = GK0*(gl2+g2) + GK1*(gl1+g1) + GK2*g0;
            hr[u][1] = GK0*(gl1+g3) + GK1*(g0+g2)  + GK2*g1;
            hr[u][2] = GK0*(g0+gr0) + GK1*(g1+g3)  + GK2*g2;
            hr[u][3] = GK0*(g1+gr1) + GK1*(g2+gr0) + GK2*g3;

            if (t >= 4) {
                const int s0=(u+1)%5, s1=(u+2)%5, s2=(u+3)%5, s3=(u+4)%5, s4=u;
                #pragma unroll
                for (int j = 0; j < 4; ++j) {
                    float bl = GK0*(hr[s0][j]+hr[s4][j]) + GK1*(hr[s1][j]+hr[s3][j]) + GK2*hr[s2][j];
                    float v  = d2[j] - bl;
                    s += v;  q = fmaf(v, v, q);
                    // histogram: x255 domain, bins over (-0.5,0.5)*255, right edge inclusive
                    if (v >= -127.5f && v <= 127.5f) {
                        int idx = (int)((v + 127.5f) * 0.19607843137254902f); // 50/255
                        idx = idx > 49 ? 49 : idx;
                        atomicAdd(&lhist[rep][idx], 1u);
                    }
                }
            }
            #pragma unroll
            for (int j = 0; j < 4; ++j) d2[j] = d1[j];
            d1[0]=g0; d1[1]=g1; d1[2]=g2; d1[3]=g3;
        }
    }

    #pragma unroll
    for (int o = 32; o > 0; o >>= 1) { s += __shfl_down(s, o); q += __shfl_down(q, o); }
    if (lane == 0) {
        atomicAdd(&gsums[WS_GRAY_OFF + b*2 + 0], s);
        atomicAdd(&gsums[WS_GRAY_OFF + b*2 + 1], q);
    }
    __syncthreads();
    if (tid < 50) {
        unsigned int h = 0;
        #pragma unroll
        for (int rr = 0; rr < 16; ++rr) h += lhist[rr][tid];
        atomicAdd(&ghist[b*50 + tid], h);
    }
}

// One block per image, thread k computes out[b,k].
__global__ __launch_bounds__(64)
void noise_final(const float* __restrict__ gsums, const unsigned int* __restrict__ ghist,
                 const float* __restrict__ W1, const float* __restrict__ b1,
                 const float* __restrict__ W2, const float* __restrict__ b2,
                 float* __restrict__ out)
{
    const int b = blockIdx.x;
    const int k = threadIdx.x;
    const float invN = 1.0f / (float)(HH*WW);
    float feats[6];
    {   // gray variance/std (undo x255 scaling)
        float s = gsums[WS_GRAY_OFF + b*2 + 0], q = gsums[WS_GRAY_OFF + b*2 + 1];
        float m = s * invN;
        float var255 = q * invN - m*m;
        var255 = var255 < 0.f ? 0.f : var255;
        float var = var255 * (1.0f/65025.0f);
        feats[0] = var; feats[1] = sqrtf(var);
    }
    {   // histogram entropy
        float tot = 0.f;
        for (int i = 0; i < 50; ++i) tot += (float)ghist[b*50 + i];
        float inv = 1.0f / (tot + 1e-10f);
        float e = 0.f;
        for (int i = 0; i < 50; ++i) {
            float p = (float)ghist[b*50 + i] * inv;
            e -= p * log2f(p + 1e-10f);
        }
        feats[2] = e;
    }
    for (int c = 0; c < 3; ++c) {
        float s = gsums[(b*3 + c)*2 + 0], q = gsums[(b*3 + c)*2 + 1];
        float m = s * invN;
        float v = q * invN - m*m;
        feats[3+c] = sqrtf(v < 0.f ? 0.f : v);
    }
    float h[32];
    #pragma unroll
    for (int i = 0; i < 32; ++i) {
        float a = b1[i];
        #pragma unroll
        for (int j = 0; j < 6; ++j) a = fmaf(feats[j], W1[i*6 + j], a);
        h[i] = a > 0.f ? a : 0.f;
    }
    float a = b2[k];
    #pragma unroll
    for (int j = 0; j < 32; ++j) a = fmaf(h[j], W2[k*32 + j], a);
    out[b*64 + k] = a > 0.f ? a : 0.f;
}

extern "C" void kernel_launch(void* const* d_in, const int* in_sizes, int n_in,
                              void* d_out, int out_size, void* d_ws, size_t ws_size,
                              hipStream_t stream) {
    (void)in_sizes; (void)n_in; (void)out_size; (void)ws_size;
    const float* x  = (const float*)d_in[0];
    const float* W1 = (const float*)d_in[1];
    const float* b1 = (const float*)d_in[2];
    const float* W2 = (const float*)d_in[3];
    const float* b2 = (const float*)d_in[4];
    float* out = (float*)d_out;

    float* gsums = (float*)d_ws;                                        // 512 floats
    unsigned int* ghist = (unsigned int*)((char*)d_ws + WS_FLOATS*4);   // [64][50]
    hipMemsetAsync(d_ws, 0, WS_FLOATS*4 + NB*50*4, stream);

    hipLaunchKernelGGL(ch_noise,  dim3(3072), dim3(256), 0, stream, x, gsums);
    hipLaunchKernelGGL(gray_hist, dim3(1024), dim3(256), 0, stream, x, gsums, ghist);
    hipLaunchKernelGGL(noise_final, dim3(64), dim3(64), 0, stream,
                       gsums, ghist, W1, b1, W2, b2, out);
}